// Round 1
// baseline (939.098 us; speedup 1.0000x reference)
//
#include <hip/hip_runtime.h>

#define NPAR 384
#define NEPI 384
#define DD   256

using bf16x8 = __bf16 __attribute__((ext_vector_type(8)));
using f32x4  = float __attribute__((ext_vector_type(4)));

__device__ __forceinline__ float sigm(float x) { return 1.0f / (1.0f + __expf(-x)); }
__device__ __forceinline__ float silu(float x) { return x / (1.0f + __expf(-x)); }
__device__ __forceinline__ unsigned short f2bf(float f) {
  unsigned u = __float_as_uint(f);
  u += 0x7fffu + ((u >> 16) & 1u);
  return (unsigned short)(u >> 16);
}
__device__ __forceinline__ float bf2f(unsigned short h) {
  return __uint_as_float(((unsigned)h) << 16);
}

// ---------------- precompute kernels ----------------

// Mr = wmix * res_w2 @ W1c ; Ma = (1-wmix) * atom_w2 @ W1c   (W1c = int_w1 rows 512..767)
__global__ void fold_kernel(const float* __restrict__ res_w2, const float* __restrict__ atom_w2,
                            const float* __restrict__ int_w1, const float* __restrict__ simw,
                            float* __restrict__ MrF, float* __restrict__ MaF) {
  const int i = blockIdx.x & 255;
  const bool isMa = blockIdx.x >= 256;
  const float wmix = 1.0f / (1.0f + __expf(-simw[0]));
  const float sc = isMa ? (1.0f - wmix) : wmix;
  const float* W2 = isMa ? atom_w2 : res_w2;
  const int j = threadIdx.x;
  float acc = 0.f;
  for (int k = 0; k < 256; ++k)
    acc += W2[i * 256 + k] * int_w1[(512 + k) * 256 + j];
  (isMa ? MaF : MrF)[i * 256 + j] = acc * sc;
}

// cvec = int_b1 + (wmix*res_b2 + (1-wmix)*atom_b2) @ W1c
__global__ void cvec_kernel(const float* __restrict__ res_b2, const float* __restrict__ atom_b2,
                            const float* __restrict__ int_b1, const float* __restrict__ int_w1,
                            const float* __restrict__ simw, float* __restrict__ cvec) {
  const int j = threadIdx.x;
  const float wmix = 1.0f / (1.0f + __expf(-simw[0]));
  float acc = int_b1[j];
  for (int k = 0; k < 256; ++k) {
    float bm = wmix * res_b2[k] + (1.0f - wmix) * atom_b2[k];
    acc += bm * int_w1[(512 + k) * 256 + j];
  }
  cvec[j] = acc;
}

// pack 7 [256,256] matrices into MFMA-native B-fragment order, bf16:
// wpack[m][((ks*16+ntile)*64 + lane)*8 + j] = B[k = ks*32 + (lane>>4)*8 + j][n = ntile*16 + (lane&15)]
__global__ void pack_kernel(const float* __restrict__ MrF, const float* __restrict__ MaF,
                            const float* __restrict__ w2, const float* __restrict__ wq,
                            const float* __restrict__ wk, const float* __restrict__ wvv,
                            const float* __restrict__ wg, unsigned short* __restrict__ wpack) {
  const int idx = blockIdx.x * 256 + threadIdx.x;   // 0 .. 7*65536-1
  const int m = idx >> 16;
  const int r = idx & 65535;
  const int chunk = r >> 9;          // ks*16 + ntile
  const int lane = (r >> 3) & 63;
  const int j = r & 7;
  const int k = (chunk >> 4) * 32 + (lane >> 4) * 8 + j;
  const int n = (chunk & 15) * 16 + (lane & 15);
  const float* src;
  switch (m) {
    case 0: src = MrF; break;
    case 1: src = MaF; break;
    case 2: src = w2; break;
    case 3: src = wq; break;
    case 4: src = wk; break;
    case 5: src = wvv; break;
    default: src = wg; break;
  }
  wpack[idx] = f2bf(src[k * 256 + n]);
}

// C[r][j] = sum_k A[r][k] * B[k][j]   (384x256 @ 256x256, fp32)
__global__ void mm_rows(const float* __restrict__ A, const float* __restrict__ B,
                        float* __restrict__ C) {
  const int r = blockIdx.x, j = threadIdx.x;
  float acc = 0.f;
  for (int k = 0; k < 256; ++k)
    acc += A[r * 256 + k] * B[k * 256 + j];
  C[r * 256 + j] = acc;
}

// ---------------- pairwise GEMM-chain kernel ----------------

__device__ __forceinline__ void zero_acc(f32x4 (&acc)[8][4]) {
#pragma unroll
  for (int mt = 0; mt < 8; ++mt)
#pragma unroll
    for (int nt = 0; nt < 4; ++nt)
      acc[mt][nt] = (f32x4){0.f, 0.f, 0.f, 0.f};
}

// acc[mt][nt] += A(ubuf)[128x256] @ Bpacked[256x256]; wave wv owns cols [wv*64, wv*64+64)
__device__ __forceinline__ void gemm_k256(f32x4 (&acc)[8][4],
                                          const unsigned short* __restrict__ wp,
                                          const unsigned short* ub, int lane, int wv) {
  const int l15 = lane & 15, l4 = lane >> 4;
#pragma unroll
  for (int ks = 0; ks < 8; ++ks) {
    bf16x8 a[8];
#pragma unroll
    for (int mt = 0; mt < 8; ++mt)
      a[mt] = *reinterpret_cast<const bf16x8*>(ub + (mt * 16 + l15) * 264 + ks * 32 + l4 * 8);
#pragma unroll
    for (int nt = 0; nt < 4; ++nt) {
      const int ntg = wv * 4 + nt;
      bf16x8 b = *reinterpret_cast<const bf16x8*>(wp + (ks * 16 + ntg) * 512 + lane * 8);
#pragma unroll
      for (int mt = 0; mt < 8; ++mt)
        acc[mt][nt] = __builtin_amdgcn_mfma_f32_16x16x32_bf16(a[mt], b, acc[mt][nt], 0, 0, 0);
    }
  }
}

__device__ __forceinline__ void store_bf16_tile(const f32x4 (&acc)[8][4],
                                                const float* __restrict__ bias,
                                                unsigned short* __restrict__ dst,
                                                int p, int e0, int l15, int l4, int wv) {
#pragma unroll
  for (int nt = 0; nt < 4; ++nt) {
    const int col = wv * 64 + nt * 16 + l15;
    const float bb = bias[col];
#pragma unroll
    for (int mt = 0; mt < 8; ++mt) {
#pragma unroll
      for (int r = 0; r < 4; ++r) {
        const int row = mt * 16 + l4 * 4 + r;
        dst[(size_t)(p * NEPI + e0 + row) * DD + col] = f2bf(acc[mt][nt][r] + bb);
      }
    }
  }
}

__global__ __launch_bounds__(256, 2) void pair_kernel(
    const float* __restrict__ Xg,
    const float* __restrict__ res_w1, const float* __restrict__ res_b1,
    const float* __restrict__ atom_w1, const float* __restrict__ atom_b1,
    const float* __restrict__ int_b2,
    const float* __restrict__ wq_b, const float* __restrict__ wk_b,
    const float* __restrict__ wv_b, const float* __restrict__ wg_b,
    const unsigned short* __restrict__ wpack, const float* __restrict__ cvec,
    const float* __restrict__ P1, const float* __restrict__ P2,
    const float* __restrict__ Hpl, const float* __restrict__ Her,
    float* __restrict__ ftri,
    unsigned short* __restrict__ Qg, unsigned short* __restrict__ Kg,
    unsigned short* __restrict__ Vg) {
  __shared__ __align__(16) unsigned short ubuf[128 * 264];
  __shared__ float Sv[128];
  __shared__ float pc[DD];
  const int t = threadIdx.x, lane = t & 63, wv = t >> 6;
  const int l15 = lane & 15, l4 = lane >> 4;
  const int blk = blockIdx.x;
  const int p = blk / 3, e0 = (blk % 3) * 128;

  if (t < 128) {
    const int e = e0 + t;
    float dx = Xg[p * 42 + 3] - Xg[(NPAR + e) * 42 + 3];
    float dy = Xg[p * 42 + 4] - Xg[(NPAR + e) * 42 + 4];
    float dz = Xg[p * 42 + 5] - Xg[(NPAR + e) * 42 + 5];
    Sv[t] = dx * dx + dy * dy + dz * dz;
  }
  pc[t] = P1[p * DD + t] + cvec[t];
  __syncthreads();

  f32x4 acc[8][4];
  zero_acc(acc);

  // phase u_r
  {
    const float w1v = res_w1[t], b1v = res_b1[t];
#pragma unroll 4
    for (int r = 0; r < 128; ++r)
      ubuf[r * 264 + t] = f2bf(silu(fmaf(Sv[r], w1v, b1v)));
  }
  __syncthreads();
  gemm_k256(acc, wpack + 0 * 65536, ubuf, lane, wv);
  __syncthreads();
  // phase u_a
  {
    const float w1v = atom_w1[t], b1v = atom_b1[t];
#pragma unroll 4
    for (int r = 0; r < 128; ++r)
      ubuf[r * 264 + t] = f2bf(silu(fmaf(Sv[r], w1v, b1v)));
  }
  __syncthreads();
  gemm_k256(acc, wpack + 1 * 65536, ubuf, lane, wv);
  __syncthreads();

  // epilogue 1: h = silu(zpre + P1[p]+cvec + P2[e]) -> ubuf
#pragma unroll
  for (int nt = 0; nt < 4; ++nt) {
    const int col = wv * 64 + nt * 16 + l15;
    const float pcc = pc[col];
#pragma unroll
    for (int mt = 0; mt < 8; ++mt) {
#pragma unroll
      for (int r = 0; r < 4; ++r) {
        const int row = mt * 16 + l4 * 4 + r;
        float z = acc[mt][nt][r] + pcc + P2[(e0 + row) * DD + col];
        ubuf[row * 264 + col] = f2bf(silu(z));
      }
    }
  }
  __syncthreads();

  // Z = h @ int_w2 + int_b2
  zero_acc(acc);
  gemm_k256(acc, wpack + 2 * 65536, ubuf, lane, wv);
  __syncthreads();
#pragma unroll
  for (int nt = 0; nt < 4; ++nt) {
    const int col = wv * 64 + nt * 16 + l15;
    const float bb = int_b2[col];
#pragma unroll
    for (int mt = 0; mt < 8; ++mt) {
#pragma unroll
      for (int r = 0; r < 4; ++r) {
        const int row = mt * 16 + l4 * 4 + r;
        ubuf[row * 264 + col] = f2bf(acc[mt][nt][r] + bb);
      }
    }
  }
  __syncthreads();

  // Q, K, V
  zero_acc(acc);
  gemm_k256(acc, wpack + 3 * 65536, ubuf, lane, wv);
  store_bf16_tile(acc, wq_b, Qg, p, e0, l15, l4, wv);
  zero_acc(acc);
  gemm_k256(acc, wpack + 4 * 65536, ubuf, lane, wv);
  store_bf16_tile(acc, wk_b, Kg, p, e0, l15, l4, wv);
  zero_acc(acc);
  gemm_k256(acc, wpack + 5 * 65536, ubuf, lane, wv);
  store_bf16_tile(acc, wv_b, Vg, p, e0, l15, l4, wv);

  // gate path: f_tri = sigmoid(Z@wg+b) * (Hpl[p] * Her[e]), summed over e
  zero_acc(acc);
  gemm_k256(acc, wpack + 6 * 65536, ubuf, lane, wv);
  float fsum[4] = {0.f, 0.f, 0.f, 0.f};
#pragma unroll
  for (int nt = 0; nt < 4; ++nt) {
    const int col = wv * 64 + nt * 16 + l15;
    const float bb = wg_b[col];
    const float hl = Hpl[p * DD + col];
#pragma unroll
    for (int mt = 0; mt < 8; ++mt) {
#pragma unroll
      for (int r = 0; r < 4; ++r) {
        const int row = mt * 16 + l4 * 4 + r;
        float g = sigm(acc[mt][nt][r] + bb);
        fsum[nt] += g * (hl * Her[(e0 + row) * DD + col]);
      }
    }
  }
#pragma unroll
  for (int nt = 0; nt < 4; ++nt) {
    float v = fsum[nt];
    v += __shfl_xor(v, 16);
    v += __shfl_xor(v, 32);
    if (lane < 16) atomicAdd(&ftri[p * DD + wv * 64 + nt * 16 + lane], v);
  }
}

// ---------------- attention kernel (one block per p) ----------------

__global__ __launch_bounds__(256, 2) void attn_kernel(
    const unsigned short* __restrict__ Qg, const unsigned short* __restrict__ Kg,
    const unsigned short* __restrict__ Vg, const float* __restrict__ ftri,
    float* __restrict__ out) {
  __shared__ float cbuf[NEPI];
  __shared__ float red[256];
  __shared__ float red2[256];
  const int t = threadIdx.x, lane = t & 63, wv = t >> 6;
  const int l15 = lane & 15, l4 = lane >> 4;
  const int p = blockIdx.x;
  for (int i = t; i < NEPI; i += 256) cbuf[i] = 0.f;
  __syncthreads();
  const unsigned short* Qp = Qg + (size_t)p * NEPI * DD;
  const unsigned short* Kp = Kg + (size_t)p * NEPI * DD;
  const float scl = 0.0625f;  // 1/sqrt(256)

  for (int rc = 0; rc < 6; ++rc) {
    const int rb = rc * 64;
    f32x4 acc[4][6];
#pragma unroll
    for (int mt = 0; mt < 4; ++mt)
#pragma unroll
      for (int nt = 0; nt < 6; ++nt) acc[mt][nt] = (f32x4){0.f, 0.f, 0.f, 0.f};

#pragma unroll
    for (int ks = 0; ks < 8; ++ks) {
      bf16x8 a[4], b[6];
#pragma unroll
      for (int mt = 0; mt < 4; ++mt)
        a[mt] = *reinterpret_cast<const bf16x8*>(Qp + (rb + mt * 16 + l15) * DD + ks * 32 + l4 * 8);
#pragma unroll
      for (int nt = 0; nt < 6; ++nt)
        b[nt] = *reinterpret_cast<const bf16x8*>(Kp + ((wv * 6 + nt) * 16 + l15) * DD + ks * 32 + l4 * 8);
#pragma unroll
      for (int nt = 0; nt < 6; ++nt)
#pragma unroll
        for (int mt = 0; mt < 4; ++mt)
          acc[mt][nt] = __builtin_amdgcn_mfma_f32_16x16x32_bf16(a[mt], b[nt], acc[mt][nt], 0, 0, 0);
    }

    // scale + wave-local row max over this wave's 96 cols
    float rmax[4][4];
#pragma unroll
    for (int mt = 0; mt < 4; ++mt) {
#pragma unroll
      for (int r = 0; r < 4; ++r) {
        float m = -1e30f;
#pragma unroll
        for (int nt = 0; nt < 6; ++nt) {
          acc[mt][nt][r] *= scl;
          m = fmaxf(m, acc[mt][nt][r]);
        }
        m = fmaxf(m, __shfl_xor(m, 1));
        m = fmaxf(m, __shfl_xor(m, 2));
        m = fmaxf(m, __shfl_xor(m, 4));
        m = fmaxf(m, __shfl_xor(m, 8));
        rmax[mt][r] = m;
      }
    }
    if (l15 == 0) {
#pragma unroll
      for (int mt = 0; mt < 4; ++mt)
#pragma unroll
        for (int r = 0; r < 4; ++r)
          red[wv * 64 + mt * 16 + l4 * 4 + r] = rmax[mt][r];
    }
    __syncthreads();
#pragma unroll
    for (int mt = 0; mt < 4; ++mt) {
#pragma unroll
      for (int r = 0; r < 4; ++r) {
        const int row = mt * 16 + l4 * 4 + r;
        rmax[mt][r] = fmaxf(fmaxf(red[row], red[64 + row]), fmaxf(red[128 + row], red[192 + row]));
      }
    }

    // exp + wave-local row sum
    float rsum[4][4];
#pragma unroll
    for (int mt = 0; mt < 4; ++mt) {
#pragma unroll
      for (int r = 0; r < 4; ++r) {
        float s = 0.f;
#pragma unroll
        for (int nt = 0; nt < 6; ++nt) {
          float e = __expf(acc[mt][nt][r] - rmax[mt][r]);
          acc[mt][nt][r] = e;
          s += e;
        }
        s += __shfl_xor(s, 1);
        s += __shfl_xor(s, 2);
        s += __shfl_xor(s, 4);
        s += __shfl_xor(s, 8);
        rsum[mt][r] = s;
      }
    }
    if (l15 == 0) {
#pragma unroll
      for (int mt = 0; mt < 4; ++mt)
#pragma unroll
        for (int r = 0; r < 4; ++r)
          red2[wv * 64 + mt * 16 + l4 * 4 + r] = rsum[mt][r];
    }
    __syncthreads();
    float rinv[4][4];
#pragma unroll
    for (int mt = 0; mt < 4; ++mt) {
#pragma unroll
      for (int r = 0; r < 4; ++r) {
        const int row = mt * 16 + l4 * 4 + r;
        rinv[mt][r] = 1.0f / (red2[row] + red2[64 + row] + red2[128 + row] + red2[192 + row]);
      }
    }

    // column sums of A into cbuf
#pragma unroll
    for (int nt = 0; nt < 6; ++nt) {
      float v = 0.f;
#pragma unroll
      for (int mt = 0; mt < 4; ++mt)
#pragma unroll
        for (int r = 0; r < 4; ++r)
          v += acc[mt][nt][r] * rinv[mt][r];
      v += __shfl_xor(v, 16);
      v += __shfl_xor(v, 32);
      if (lane < 16) cbuf[wv * 96 + nt * 16 + lane] += v;
    }
    __syncthreads();
  }

  // out[p] = (ftri_sum + sum_f c[f] * V[f]) / NE
  const unsigned short* Vp = Vg + (size_t)p * NEPI * DD;
  float a0 = ftri[p * DD + t], a1 = 0.f, a2 = 0.f, a3 = 0.f;
  for (int f = 0; f < NEPI; f += 4) {
    a0 = fmaf(cbuf[f + 0], bf2f(Vp[(f + 0) * DD + t]), a0);
    a1 = fmaf(cbuf[f + 1], bf2f(Vp[(f + 1) * DD + t]), a1);
    a2 = fmaf(cbuf[f + 2], bf2f(Vp[(f + 2) * DD + t]), a2);
    a3 = fmaf(cbuf[f + 3], bf2f(Vp[(f + 3) * DD + t]), a3);
  }
  out[p * DD + t] = (a0 + a1 + a2 + a3) * (1.0f / 384.0f);
}

// ---------------- launch ----------------

extern "C" void kernel_launch(void* const* d_in, const int* in_sizes, int n_in,
                              void* d_out, int out_size, void* d_ws, size_t ws_size,
                              hipStream_t stream) {
  (void)in_sizes; (void)n_in; (void)out_size; (void)ws_size;
  const float* H = (const float*)d_in[0];
  const float* X = (const float*)d_in[1];
  const float* res_w1 = (const float*)d_in[4];
  const float* res_b1 = (const float*)d_in[5];
  const float* res_w2 = (const float*)d_in[6];
  const float* res_b2 = (const float*)d_in[7];
  const float* atom_w1 = (const float*)d_in[8];
  const float* atom_b1 = (const float*)d_in[9];
  const float* atom_w2 = (const float*)d_in[10];
  const float* atom_b2 = (const float*)d_in[11];
  const float* simw = (const float*)d_in[12];
  const float* int_w1 = (const float*)d_in[13];
  const float* int_b1 = (const float*)d_in[14];
  const float* int_w2 = (const float*)d_in[15];
  const float* int_b2 = (const float*)d_in[16];
  const float* wl = (const float*)d_in[17];
  const float* wr = (const float*)d_in[18];
  const float* wg_w = (const float*)d_in[19];
  const float* wg_b = (const float*)d_in[20];
  const float* wq_w = (const float*)d_in[21];
  const float* wq_b = (const float*)d_in[22];
  const float* wk_w = (const float*)d_in[23];
  const float* wk_b = (const float*)d_in[24];
  const float* wv_w = (const float*)d_in[25];
  const float* wv_b = (const float*)d_in[26];

  char* ws = (char*)d_ws;
  unsigned short* wpack = (unsigned short*)(ws + 0);          //   917504 B
  float* MrF  = (float*)(ws + 917504);                        //   262144 B
  float* MaF  = (float*)(ws + 1179648);                       //   262144 B
  float* cvec = (float*)(ws + 1441792);                       //     1024 B
  float* P1   = (float*)(ws + 1442816);                       //   393216 B
  float* P2   = (float*)(ws + 1836032);                       //   393216 B
  float* Hpl  = (float*)(ws + 2229248);                       //   393216 B
  float* Her  = (float*)(ws + 2622464);                       //   393216 B
  float* ftri = (float*)(ws + 3015680);                       //   393216 B
  unsigned short* Qb = (unsigned short*)(ws + 3408896);       // 75497472 B
  unsigned short* Kb = (unsigned short*)(ws + 78906368);      // 75497472 B
  unsigned short* Vb = (unsigned short*)(ws + 154403840);     // 75497472 B

  hipMemsetAsync(ftri, 0, NPAR * DD * sizeof(float), stream);
  fold_kernel<<<512, 256, 0, stream>>>(res_w2, atom_w2, int_w1, simw, MrF, MaF);
  cvec_kernel<<<1, 256, 0, stream>>>(res_b2, atom_b2, int_b1, int_w1, simw, cvec);
  pack_kernel<<<1792, 256, 0, stream>>>(MrF, MaF, int_w2, wq_w, wk_w, wv_w, wg_w, wpack);
  mm_rows<<<384, 256, 0, stream>>>(H, wl, Hpl);
  mm_rows<<<384, 256, 0, stream>>>(H + NPAR * DD, wr, Her);
  mm_rows<<<384, 256, 0, stream>>>(H, int_w1, P1);
  mm_rows<<<384, 256, 0, stream>>>(H + NPAR * DD, int_w1 + DD * DD, P2);
  pair_kernel<<<1152, 256, 0, stream>>>(X, res_w1, res_b1, atom_w1, atom_b1,
                                        int_b2, wq_b, wk_b, wv_b, wg_b, wpack, cvec,
                                        P1, P2, Hpl, Her, ftri, Qb, Kb, Vb);
  attn_kernel<<<384, 256, 0, stream>>>(Qb, Kb, Vb, ftri, (float*)d_out);
  hipMemcpyAsync((float*)d_out + NPAR * DD, H + NPAR * DD,
                 (1024 - NPAR) * DD * sizeof(float), hipMemcpyDeviceToDevice, stream);
}

// Round 2
// 674.410 us; speedup vs baseline: 1.3925x; 1.3925x over previous
//
#include <hip/hip_runtime.h>

#define NPAR 384
#define NEPI 384
#define DD   256

using bf16x8 = __bf16 __attribute__((ext_vector_type(8)));
using f32x4  = float __attribute__((ext_vector_type(4)));

__device__ __forceinline__ float sigm(float x) { return 1.0f / (1.0f + __expf(-x)); }
__device__ __forceinline__ float silu(float x) { return x / (1.0f + __expf(-x)); }
__device__ __forceinline__ unsigned short f2bf(float f) {
  unsigned u = __float_as_uint(f);
  u += 0x7fffu + ((u >> 16) & 1u);
  return (unsigned short)(u >> 16);
}
__device__ __forceinline__ float bf2f(unsigned short h) {
  return __uint_as_float(((unsigned)h) << 16);
}
__device__ __forceinline__ uint2 pack4(float a, float b, float c, float d) {
  uint2 r;
  r.x = (unsigned)f2bf(a) | ((unsigned)f2bf(b) << 16);
  r.y = (unsigned)f2bf(c) | ((unsigned)f2bf(d) << 16);
  return r;
}

// ---------------- precompute kernels ----------------

__global__ void fold_kernel(const float* __restrict__ res_w2, const float* __restrict__ atom_w2,
                            const float* __restrict__ int_w1, const float* __restrict__ simw,
                            float* __restrict__ MrF, float* __restrict__ MaF) {
  const int i = blockIdx.x & 255;
  const bool isMa = blockIdx.x >= 256;
  const float wmix = 1.0f / (1.0f + __expf(-simw[0]));
  const float sc = isMa ? (1.0f - wmix) : wmix;
  const float* W2 = isMa ? atom_w2 : res_w2;
  const int j = threadIdx.x;
  float acc = 0.f;
  for (int k = 0; k < 256; ++k)
    acc += W2[i * 256 + k] * int_w1[(512 + k) * 256 + j];
  (isMa ? MaF : MrF)[i * 256 + j] = acc * sc;
}

__global__ void cvec_kernel(const float* __restrict__ res_b2, const float* __restrict__ atom_b2,
                            const float* __restrict__ int_b1, const float* __restrict__ int_w1,
                            const float* __restrict__ simw, float* __restrict__ cvec) {
  const int j = threadIdx.x;
  const float wmix = 1.0f / (1.0f + __expf(-simw[0]));
  float acc = int_b1[j];
  for (int k = 0; k < 256; ++k) {
    float bm = wmix * res_b2[k] + (1.0f - wmix) * atom_b2[k];
    acc += bm * int_w1[(512 + k) * 256 + j];
  }
  cvec[j] = acc;
}

// pack 7 [256,256] matrices into MFMA fragment order (B-operand == transposed A-operand):
// wpack[m][((ks*16+tile)*64 + lane)*8 + j] = W[k = ks*32 + (lane>>4)*8 + j][n = tile*16 + (lane&15)]
__global__ void pack_kernel(const float* __restrict__ MrF, const float* __restrict__ MaF,
                            const float* __restrict__ w2, const float* __restrict__ wq,
                            const float* __restrict__ wk, const float* __restrict__ wvv,
                            const float* __restrict__ wg, unsigned short* __restrict__ wpack) {
  const int idx = blockIdx.x * 256 + threadIdx.x;
  const int m = idx >> 16;
  const int r = idx & 65535;
  const int chunk = r >> 9;
  const int lane = (r >> 3) & 63;
  const int j = r & 7;
  const int k = (chunk >> 4) * 32 + (lane >> 4) * 8 + j;
  const int n = (chunk & 15) * 16 + (lane & 15);
  const float* src;
  switch (m) {
    case 0: src = MrF; break;
    case 1: src = MaF; break;
    case 2: src = w2; break;
    case 3: src = wq; break;
    case 4: src = wk; break;
    case 5: src = wvv; break;
    default: src = wg; break;
  }
  wpack[idx] = f2bf(src[k * 256 + n]);
}

__global__ void mm_rows(const float* __restrict__ A, const float* __restrict__ B,
                        float* __restrict__ C) {
  const int r = blockIdx.x, j = threadIdx.x;
  float acc = 0.f;
  for (int k = 0; k < 256; ++k)
    acc += A[r * 256 + k] * B[k * 256 + j];
  C[r * 256 + j] = acc;
}

// ---------------- pairwise GEMM-chain kernel (transposed acc: lane holds 4 contiguous d) --------

__device__ __forceinline__ void zero_acc(f32x4 (&acc)[4][8]) {
#pragma unroll
  for (int mt = 0; mt < 4; ++mt)
#pragma unroll
    for (int nt = 0; nt < 8; ++nt)
      acc[mt][nt] = (f32x4){0.f, 0.f, 0.f, 0.f};
}

// acc^T[d][e]: d = wv*64 + mt*16 + l4*4 + r, e = nt*16 + l15.
// mfma(Wfrag, ActFrag): A-operand = W^T (same packed data), B-operand = Act^T (same LDS frag).
__device__ __forceinline__ void gemm_k256(f32x4 (&acc)[4][8],
                                          const unsigned short* __restrict__ wp,
                                          const unsigned short* ub, int lane, int wv) {
  const int l15 = lane & 15, l4 = lane >> 4;
#pragma unroll
  for (int ks = 0; ks < 8; ++ks) {
    bf16x8 a[4];
#pragma unroll
    for (int mt = 0; mt < 4; ++mt)
      a[mt] = *reinterpret_cast<const bf16x8*>(wp + ((ks * 16 + wv * 4 + mt) * 64 + lane) * 8);
#pragma unroll
    for (int nt = 0; nt < 8; ++nt) {
      bf16x8 b = *reinterpret_cast<const bf16x8*>(ub + (nt * 16 + l15) * 264 + ks * 32 + l4 * 8);
#pragma unroll
      for (int mt = 0; mt < 4; ++mt)
        acc[mt][nt] = __builtin_amdgcn_mfma_f32_16x16x32_bf16(a[mt], b, acc[mt][nt], 0, 0, 0);
    }
  }
}

__device__ __forceinline__ void store_bf16_tile(const f32x4 (&acc)[4][8],
                                                const float* __restrict__ bias,
                                                unsigned short* __restrict__ dst,
                                                int p, int e0, int d0, int l15, int l4) {
#pragma unroll
  for (int mt = 0; mt < 4; ++mt) {
    const int d = d0 + mt * 16 + l4 * 4;
    const f32x4 bb = *reinterpret_cast<const f32x4*>(&bias[d]);
#pragma unroll
    for (int nt = 0; nt < 8; ++nt) {
      const int e = e0 + nt * 16 + l15;
      uint2 pk = pack4(acc[mt][nt][0] + bb[0], acc[mt][nt][1] + bb[1],
                       acc[mt][nt][2] + bb[2], acc[mt][nt][3] + bb[3]);
      *reinterpret_cast<uint2*>(&dst[(size_t)(p * NEPI + e) * DD + d]) = pk;
    }
  }
}

__global__ __launch_bounds__(256, 2) void pair_kernel(
    const float* __restrict__ Xg,
    const float* __restrict__ res_w1, const float* __restrict__ res_b1,
    const float* __restrict__ atom_w1, const float* __restrict__ atom_b1,
    const float* __restrict__ int_b2,
    const float* __restrict__ wq_b, const float* __restrict__ wk_b,
    const float* __restrict__ wv_b, const float* __restrict__ wg_b,
    const unsigned short* __restrict__ wpack, const float* __restrict__ cvec,
    const float* __restrict__ P1, const float* __restrict__ P2,
    const float* __restrict__ Hpl, const float* __restrict__ Her,
    float* __restrict__ ftri,
    unsigned short* __restrict__ Qg, unsigned short* __restrict__ Kg,
    unsigned short* __restrict__ Vg) {
  __shared__ __align__(16) unsigned short ubuf[128 * 264];
  __shared__ float Sv[128];
  __shared__ float pc[DD];
  const int t = threadIdx.x, lane = t & 63, wv = t >> 6;
  const int l15 = lane & 15, l4 = lane >> 4;
  const int p = blockIdx.x / 3, e0 = (blockIdx.x % 3) * 128;
  const int d0 = wv * 64;

  if (t < 128) {
    const int e = e0 + t;
    float dx = Xg[p * 42 + 3] - Xg[(NPAR + e) * 42 + 3];
    float dy = Xg[p * 42 + 4] - Xg[(NPAR + e) * 42 + 4];
    float dz = Xg[p * 42 + 5] - Xg[(NPAR + e) * 42 + 5];
    Sv[t] = dx * dx + dy * dy + dz * dz;
  }
  pc[t] = P1[p * DD + t] + cvec[t];
  __syncthreads();

  f32x4 acc[4][8];
  zero_acc(acc);

  // fill u_r: lane owns d-quad lane*4, wave owns rows wv, wv+4, ...
  {
    const f32x4 w1q = *reinterpret_cast<const f32x4*>(&res_w1[lane * 4]);
    const f32x4 b1q = *reinterpret_cast<const f32x4*>(&res_b1[lane * 4]);
#pragma unroll 4
    for (int e = wv; e < 128; e += 4) {
      const float s = Sv[e];
      uint2 pk = pack4(silu(fmaf(s, w1q[0], b1q[0])), silu(fmaf(s, w1q[1], b1q[1])),
                       silu(fmaf(s, w1q[2], b1q[2])), silu(fmaf(s, w1q[3], b1q[3])));
      *reinterpret_cast<uint2*>(&ubuf[e * 264 + lane * 4]) = pk;
    }
  }
  __syncthreads();
  gemm_k256(acc, wpack + 0 * 65536, ubuf, lane, wv);
  __syncthreads();
  // fill u_a
  {
    const f32x4 w1q = *reinterpret_cast<const f32x4*>(&atom_w1[lane * 4]);
    const f32x4 b1q = *reinterpret_cast<const f32x4*>(&atom_b1[lane * 4]);
#pragma unroll 4
    for (int e = wv; e < 128; e += 4) {
      const float s = Sv[e];
      uint2 pk = pack4(silu(fmaf(s, w1q[0], b1q[0])), silu(fmaf(s, w1q[1], b1q[1])),
                       silu(fmaf(s, w1q[2], b1q[2])), silu(fmaf(s, w1q[3], b1q[3])));
      *reinterpret_cast<uint2*>(&ubuf[e * 264 + lane * 4]) = pk;
    }
  }
  __syncthreads();
  gemm_k256(acc, wpack + 1 * 65536, ubuf, lane, wv);
  __syncthreads();

  // epilogue: h = silu(zpre^T + pc[d] + P2[e][d]) -> ubuf[e][d]
#pragma unroll
  for (int mt = 0; mt < 4; ++mt) {
    const int d = d0 + mt * 16 + l4 * 4;
    const f32x4 pcv = *reinterpret_cast<const f32x4*>(&pc[d]);
#pragma unroll
    for (int nt = 0; nt < 8; ++nt) {
      const int e = nt * 16 + l15;
      const f32x4 p2v = *reinterpret_cast<const f32x4*>(&P2[(e0 + e) * DD + d]);
      uint2 pk = pack4(silu(acc[mt][nt][0] + pcv[0] + p2v[0]),
                       silu(acc[mt][nt][1] + pcv[1] + p2v[1]),
                       silu(acc[mt][nt][2] + pcv[2] + p2v[2]),
                       silu(acc[mt][nt][3] + pcv[3] + p2v[3]));
      *reinterpret_cast<uint2*>(&ubuf[e * 264 + d]) = pk;
    }
  }
  __syncthreads();

  // Z = h @ int_w2 + int_b2
  zero_acc(acc);
  gemm_k256(acc, wpack + 2 * 65536, ubuf, lane, wv);
  __syncthreads();
#pragma unroll
  for (int mt = 0; mt < 4; ++mt) {
    const int d = d0 + mt * 16 + l4 * 4;
    const f32x4 bb = *reinterpret_cast<const f32x4*>(&int_b2[d]);
#pragma unroll
    for (int nt = 0; nt < 8; ++nt) {
      const int e = nt * 16 + l15;
      uint2 pk = pack4(acc[mt][nt][0] + bb[0], acc[mt][nt][1] + bb[1],
                       acc[mt][nt][2] + bb[2], acc[mt][nt][3] + bb[3]);
      *reinterpret_cast<uint2*>(&ubuf[e * 264 + d]) = pk;
    }
  }
  __syncthreads();

  // Q, K, V
  zero_acc(acc);
  gemm_k256(acc, wpack + 3 * 65536, ubuf, lane, wv);
  store_bf16_tile(acc, wq_b, Qg, p, e0, d0, l15, l4);
  zero_acc(acc);
  gemm_k256(acc, wpack + 4 * 65536, ubuf, lane, wv);
  store_bf16_tile(acc, wk_b, Kg, p, e0, d0, l15, l4);
  zero_acc(acc);
  gemm_k256(acc, wpack + 5 * 65536, ubuf, lane, wv);
  store_bf16_tile(acc, wv_b, Vg, p, e0, d0, l15, l4);

  // gate: f_tri[d] += sum_e sigm(Zg^T + b) * Hpl[p][d] * Her[e][d]
  zero_acc(acc);
  gemm_k256(acc, wpack + 6 * 65536, ubuf, lane, wv);
#pragma unroll
  for (int mt = 0; mt < 4; ++mt) {
    const int d = d0 + mt * 16 + l4 * 4;
    const f32x4 bb = *reinterpret_cast<const f32x4*>(&wg_b[d]);
    const f32x4 hl = *reinterpret_cast<const f32x4*>(&Hpl[p * DD + d]);
    f32x4 fs = (f32x4){0.f, 0.f, 0.f, 0.f};
#pragma unroll
    for (int nt = 0; nt < 8; ++nt) {
      const int e = e0 + nt * 16 + l15;
      const f32x4 hr = *reinterpret_cast<const f32x4*>(&Her[e * DD + d]);
#pragma unroll
      for (int r = 0; r < 4; ++r)
        fs[r] += sigm(acc[mt][nt][r] + bb[r]) * hl[r] * hr[r];
    }
#pragma unroll
    for (int r = 0; r < 4; ++r) {
      float v = fs[r];
      v += __shfl_xor(v, 1);
      v += __shfl_xor(v, 2);
      v += __shfl_xor(v, 4);
      v += __shfl_xor(v, 8);
      if (l15 == 0) atomicAdd(&ftri[p * DD + d + r], v);
    }
  }
}

// ---------------- attention kernel: (p, row-chunk) per block ----------------

__global__ __launch_bounds__(256) void attn_kernel(
    const unsigned short* __restrict__ Qg, const unsigned short* __restrict__ Kg,
    float* __restrict__ cbufg) {
  __shared__ float red[256];
  __shared__ float red2[256];
  const int t = threadIdx.x, lane = t & 63, wv = t >> 6;
  const int l15 = lane & 15, l4 = lane >> 4;
  const int p = blockIdx.x / 6, rb = (blockIdx.x % 6) * 64;
  const unsigned short* Qp = Qg + (size_t)p * NEPI * DD;
  const unsigned short* Kp = Kg + (size_t)p * NEPI * DD;
  const float scl = 0.0625f;

  f32x4 acc[4][6];
#pragma unroll
  for (int mt = 0; mt < 4; ++mt)
#pragma unroll
    for (int nt = 0; nt < 6; ++nt) acc[mt][nt] = (f32x4){0.f, 0.f, 0.f, 0.f};

#pragma unroll
  for (int ks = 0; ks < 8; ++ks) {
    bf16x8 a[4], b[6];
#pragma unroll
    for (int mt = 0; mt < 4; ++mt)
      a[mt] = *reinterpret_cast<const bf16x8*>(Qp + (rb + mt * 16 + l15) * DD + ks * 32 + l4 * 8);
#pragma unroll
    for (int nt = 0; nt < 6; ++nt)
      b[nt] = *reinterpret_cast<const bf16x8*>(Kp + ((wv * 6 + nt) * 16 + l15) * DD + ks * 32 + l4 * 8);
#pragma unroll
    for (int nt = 0; nt < 6; ++nt)
#pragma unroll
      for (int mt = 0; mt < 4; ++mt)
        acc[mt][nt] = __builtin_amdgcn_mfma_f32_16x16x32_bf16(a[mt], b[nt], acc[mt][nt], 0, 0, 0);
  }

  // row max over this wave's 96 cols, then cross-wave
  float rmax[4][4];
#pragma unroll
  for (int mt = 0; mt < 4; ++mt) {
#pragma unroll
    for (int r = 0; r < 4; ++r) {
      float m = -1e30f;
#pragma unroll
      for (int nt = 0; nt < 6; ++nt) {
        acc[mt][nt][r] *= scl;
        m = fmaxf(m, acc[mt][nt][r]);
      }
      m = fmaxf(m, __shfl_xor(m, 1));
      m = fmaxf(m, __shfl_xor(m, 2));
      m = fmaxf(m, __shfl_xor(m, 4));
      m = fmaxf(m, __shfl_xor(m, 8));
      rmax[mt][r] = m;
    }
  }
  if (l15 == 0) {
#pragma unroll
    for (int mt = 0; mt < 4; ++mt)
#pragma unroll
      for (int r = 0; r < 4; ++r)
        red[wv * 64 + mt * 16 + l4 * 4 + r] = rmax[mt][r];
  }
  __syncthreads();
#pragma unroll
  for (int mt = 0; mt < 4; ++mt) {
#pragma unroll
    for (int r = 0; r < 4; ++r) {
      const int row = mt * 16 + l4 * 4 + r;
      rmax[mt][r] = fmaxf(fmaxf(red[row], red[64 + row]), fmaxf(red[128 + row], red[192 + row]));
    }
  }

  float rsum[4][4];
#pragma unroll
  for (int mt = 0; mt < 4; ++mt) {
#pragma unroll
    for (int r = 0; r < 4; ++r) {
      float s = 0.f;
#pragma unroll
      for (int nt = 0; nt < 6; ++nt) {
        float e = __expf(acc[mt][nt][r] - rmax[mt][r]);
        acc[mt][nt][r] = e;
        s += e;
      }
      s += __shfl_xor(s, 1);
      s += __shfl_xor(s, 2);
      s += __shfl_xor(s, 4);
      s += __shfl_xor(s, 8);
      rsum[mt][r] = s;
    }
  }
  if (l15 == 0) {
#pragma unroll
    for (int mt = 0; mt < 4; ++mt)
#pragma unroll
      for (int r = 0; r < 4; ++r)
        red2[wv * 64 + mt * 16 + l4 * 4 + r] = rsum[mt][r];
  }
  __syncthreads();
  float rinv[4][4];
#pragma unroll
  for (int mt = 0; mt < 4; ++mt) {
#pragma unroll
    for (int r = 0; r < 4; ++r) {
      const int row = mt * 16 + l4 * 4 + r;
      rinv[mt][r] = 1.0f / (red2[row] + red2[64 + row] + red2[128 + row] + red2[192 + row]);
    }
  }

  // column sums of A for this 64-row chunk -> global accumulate
#pragma unroll
  for (int nt = 0; nt < 6; ++nt) {
    float v = 0.f;
#pragma unroll
    for (int mt = 0; mt < 4; ++mt)
#pragma unroll
      for (int r = 0; r < 4; ++r)
        v += acc[mt][nt][r] * rinv[mt][r];
    v += __shfl_xor(v, 16);
    v += __shfl_xor(v, 32);
    if (lane < 16) atomicAdd(&cbufg[p * NEPI + wv * 96 + nt * 16 + lane], v);
  }
}

// ---------------- output kernel ----------------

__global__ __launch_bounds__(256) void out_kernel(
    const unsigned short* __restrict__ Vg, const float* __restrict__ ftri,
    const float* __restrict__ cbufg, float* __restrict__ out) {
  __shared__ float cb[NEPI];
  const int p = blockIdx.x, t = threadIdx.x;
  for (int i = t; i < NEPI; i += 256) cb[i] = cbufg[p * NEPI + i];
  __syncthreads();
  const unsigned short* Vp = Vg + (size_t)p * NEPI * DD;
  float a0 = ftri[p * DD + t], a1 = 0.f, a2 = 0.f, a3 = 0.f;
  for (int f = 0; f < NEPI; f += 4) {
    a0 = fmaf(cb[f + 0], bf2f(Vp[(f + 0) * DD + t]), a0);
    a1 = fmaf(cb[f + 1], bf2f(Vp[(f + 1) * DD + t]), a1);
    a2 = fmaf(cb[f + 2], bf2f(Vp[(f + 2) * DD + t]), a2);
    a3 = fmaf(cb[f + 3], bf2f(Vp[(f + 3) * DD + t]), a3);
  }
  out[p * DD + t] = (a0 + a1 + a2 + a3) * (1.0f / 384.0f);
}

// ---------------- launch ----------------

extern "C" void kernel_launch(void* const* d_in, const int* in_sizes, int n_in,
                              void* d_out, int out_size, void* d_ws, size_t ws_size,
                              hipStream_t stream) {
  (void)in_sizes; (void)n_in; (void)out_size; (void)ws_size;
  const float* H = (const float*)d_in[0];
  const float* X = (const float*)d_in[1];
  const float* res_w1 = (const float*)d_in[4];
  const float* res_b1 = (const float*)d_in[5];
  const float* res_w2 = (const float*)d_in[6];
  const float* res_b2 = (const float*)d_in[7];
  const float* atom_w1 = (const float*)d_in[8];
  const float* atom_b1 = (const float*)d_in[9];
  const float* atom_w2 = (const float*)d_in[10];
  const float* atom_b2 = (const float*)d_in[11];
  const float* simw = (const float*)d_in[12];
  const float* int_w1 = (const float*)d_in[13];
  const float* int_b1 = (const float*)d_in[14];
  const float* int_w2 = (const float*)d_in[15];
  const float* int_b2 = (const float*)d_in[16];
  const float* wl = (const float*)d_in[17];
  const float* wr = (const float*)d_in[18];
  const float* wg_w = (const float*)d_in[19];
  const float* wg_b = (const float*)d_in[20];
  const float* wq_w = (const float*)d_in[21];
  const float* wq_b = (const float*)d_in[22];
  const float* wk_w = (const float*)d_in[23];
  const float* wk_b = (const float*)d_in[24];
  const float* wv_w = (const float*)d_in[25];
  const float* wv_b = (const float*)d_in[26];

  char* ws = (char*)d_ws;
  unsigned short* wpack = (unsigned short*)(ws + 0);          //   917504 B
  float* MrF  = (float*)(ws + 917504);
  float* MaF  = (float*)(ws + 1179648);
  float* cvec = (float*)(ws + 1441792);
  float* P1   = (float*)(ws + 1442816);
  float* P2   = (float*)(ws + 1836032);
  float* Hpl  = (float*)(ws + 2229248);
  float* Her  = (float*)(ws + 2622464);
  float* ftri = (float*)(ws + 3015680);
  unsigned short* Qb = (unsigned short*)(ws + 3408896);       // 75497472 B
  unsigned short* Kb = (unsigned short*)(ws + 78906368);      // 75497472 B
  unsigned short* Vb = (unsigned short*)(ws + 154403840);     // 75497472 B
  float* cbufg = (float*)(ws + 229901312);                    //   589824 B

  hipMemsetAsync(ftri, 0, NPAR * DD * sizeof(float), stream);
  hipMemsetAsync(cbufg, 0, NPAR * NEPI * sizeof(float), stream);
  fold_kernel<<<512, 256, 0, stream>>>(res_w2, atom_w2, int_w1, simw, MrF, MaF);
  cvec_kernel<<<1, 256, 0, stream>>>(res_b2, atom_b2, int_b1, int_w1, simw, cvec);
  pack_kernel<<<1792, 256, 0, stream>>>(MrF, MaF, int_w2, wq_w, wk_w, wv_w, wg_w, wpack);
  mm_rows<<<384, 256, 0, stream>>>(H, wl, Hpl);
  mm_rows<<<384, 256, 0, stream>>>(H + NPAR * DD, wr, Her);
  mm_rows<<<384, 256, 0, stream>>>(H, int_w1, P1);
  mm_rows<<<384, 256, 0, stream>>>(H + NPAR * DD, int_w1 + DD * DD, P2);
  pair_kernel<<<1152, 256, 0, stream>>>(X, res_w1, res_b1, atom_w1, atom_b1,
                                        int_b2, wq_b, wk_b, wv_b, wg_b, wpack, cvec,
                                        P1, P2, Hpl, Her, ftri, Qb, Kb, Vb);
  attn_kernel<<<2304, 256, 0, stream>>>(Qb, Kb, cbufg);
  out_kernel<<<384, 256, 0, stream>>>(Vb, ftri, cbufg, (float*)d_out);
  hipMemcpyAsync((float*)d_out + NPAR * DD, H + NPAR * DD,
                 (1024 - NPAR) * DD * sizeof(float), hipMemcpyDeviceToDevice, stream);
}